// Round 4
// baseline (149.706 us; speedup 1.0000x reference)
//
#include <hip/hip_runtime.h>
#include <hip/hip_bf16.h>
#include <math.h>

#define D   2048
#define NQ  1024
#define BSZ 64
#define NC  65
#define HD  128

// workspace offsets (floats)
#define OFF_SCALEH 0
#define OFF_CH     128
#define OFF_BZC    256
#define OFF_BAC    384
#define OFF_BVEC   512
#define OFF_PXP    640
#define OFF_WC     896
#define OFF_A2T    6016
#define OFF_B2     14208
#define OFF_SP     145280
#define OFF_ZT     669568
#define OFF_FNB    751488
#define OFF_AFB    817024
#define OFF_EMBB   882560
#define OFF_W1T    1931136
#define OFF_WZT    2062208
#define OFF_WAT    2070400
#define OFF_MW2B   2078592
#define OFF_CWT    2226048
#define OFF_H1P    2307968
// total 2586496 fl = 10.35 MB

typedef __attribute__((ext_vector_type(8))) short    bf16x8;
typedef __attribute__((ext_vector_type(4))) float    f32x4;
typedef __attribute__((ext_vector_type(8))) unsigned short u16x8;
typedef __attribute__((ext_vector_type(2))) unsigned short u16x2;

__device__ inline unsigned short f2b(float v) {
    __hip_bfloat16 h = __float2bfloat16(v);
    return __builtin_bit_cast(unsigned short, h);
}

// ===================== K1: prep (block-role dispatch, 256 thr) =====================
// [0] pre_small | [1,129) pre_W | [129,165) mw2b 4-row | [165,181) clf_wT
// [181,245) rnorm | [245,757) emb-cvt 2-row | [757,821) w1t
__global__ void __launch_bounds__(256) k_prep(const float* __restrict__ all_f,
                                              const float* __restrict__ emb,
                                              const float* __restrict__ head_w1,
                                              const float* __restrict__ head_b1,
                                              const float* __restrict__ head_g,
                                              const float* __restrict__ head_beta,
                                              const float* __restrict__ head_rm,
                                              const float* __restrict__ head_rv,
                                              const float* __restrict__ head_w2,
                                              const float* __restrict__ head_b2,
                                              const float* __restrict__ mix_w1,
                                              const float* __restrict__ mix_b1,
                                              const float* __restrict__ mix_g,
                                              const float* __restrict__ mix_beta,
                                              const float* __restrict__ mix_rm,
                                              const float* __restrict__ mix_rv,
                                              const float* __restrict__ mix_w2,
                                              const float* __restrict__ mix_b2,
                                              const float* __restrict__ clf_w,
                                              float* __restrict__ ws) {
    __shared__ float sbuf[128*66];
    int bid = blockIdx.x, t = threadIdx.x;
    if (bid == 0) {
        int h = t & 127, jq = t >> 7;
        float sb = 0.f, sa = 0.f;
        #pragma unroll 8
        for (int j = jq*64; j < jq*64 + 64; ++j) {
            float b2v = head_b2[j];
            sb = fmaf(b2v, mix_w1[(HD + j)*HD + h], sb);
            sa = fmaf(b2v, mix_w1[j*HD + h], sa);
        }
        sbuf[jq*256 + h]       = sb;
        sbuf[jq*256 + 128 + h] = sa;
        __syncthreads();
        if (jq == 0) {
            float s = head_g[h] * rsqrtf(head_rv[h] + 1e-5f);
            ws[OFF_SCALEH + h] = s;
            ws[OFF_CH + h] = (head_b1[h] - head_rm[h]) * s + head_beta[h];
            float ms = mix_g[h] * rsqrtf(mix_rv[h] + 1e-5f);
            float msh = mix_beta[h] - mix_rm[h] * ms;
            float sbT = sbuf[h] + sbuf[256 + h];
            float saT = sbuf[128 + h] + sbuf[256 + 128 + h];
            ws[OFF_BZC + h] = sbT * ms;
            ws[OFF_BAC + h] = fmaf(saT + mix_b1[h], ms, msh);
        }
    } else if (bid < 129) {
        int j = bid - 1;
        int h = t & 127, which = t >> 7;
        const float* M1 = mix_w1 + (which ? 0 : HD*HD);
        float ms = mix_g[h] * rsqrtf(mix_rv[h] + 1e-5f);
        float acc = 0.f;
        #pragma unroll 8
        for (int k = 0; k < HD; ++k)
            acc = fmaf(head_w2[j*HD + k], M1[k*HD + h], acc);
        unsigned short* dst = (unsigned short*)(ws + (which ? OFF_WAT : OFF_WZT));
        dst[h*HD + j] = f2b(acc * ms);
    } else if (bid < 165) {
        int r0 = (bid - 129) * 4;
        unsigned short* dst = (unsigned short*)(ws + OFF_MW2B);
        int i0 = t * 8;
        for (int rr = 0; rr < 4; ++rr) {
            int r = r0 + rr;
            u16x8 o;
            if (r < HD || r == HD) {
                const float* src = (r < HD) ? (mix_w2 + (size_t)r * D) : mix_b2;
                float4 f1 = *(const float4*)(src + i0);
                float4 f2 = *(const float4*)(src + i0 + 4);
                o[0]=f2b(f1.x); o[1]=f2b(f1.y); o[2]=f2b(f1.z); o[3]=f2b(f1.w);
                o[4]=f2b(f2.x); o[5]=f2b(f2.y); o[6]=f2b(f2.z); o[7]=f2b(f2.w);
            } else {
                o[0]=0;o[1]=0;o[2]=0;o[3]=0;o[4]=0;o[5]=0;o[6]=0;o[7]=0;
            }
            *(u16x8*)(dst + (size_t)r*D + i0) = o;
        }
    } else if (bid < 181) {
        int k0 = (bid - 165) * 128;
        float (*tile)[66] = (float(*)[66])sbuf;
        for (int i = t; i < 128*65; i += 256) {
            int r = i / 65;
            tile[r][i - 65*r] = clf_w[(size_t)k0*65 + i];
        }
        __syncthreads();
        unsigned short* cwt = (unsigned short*)(ws + OFF_CWT);
        for (int idx = t; idx < 80*16; idx += 256) {
            int c = idx >> 4, kq = idx & 15;
            u16x8 v;
            #pragma unroll
            for (int j = 0; j < 8; ++j)
                v[j] = (c < NC) ? f2b(tile[kq*8 + j][c]) : (unsigned short)0;
            *(u16x8*)(cwt + (size_t)c*D + k0 + kq*8) = v;
        }
    } else if (bid < 245) {
        int b = bid - 181;
        const float* src = all_f + (size_t)b * D;
        int i0 = t * 8;
        float4 f1 = *(const float4*)(src + i0);
        float4 f2 = *(const float4*)(src + i0 + 4);
        float s = f1.x*f1.x + f1.y*f1.y + f1.z*f1.z + f1.w*f1.w
                + f2.x*f2.x + f2.y*f2.y + f2.z*f2.z + f2.w*f2.w;
        s += __shfl_xor(s, 1);  s += __shfl_xor(s, 2);  s += __shfl_xor(s, 4);
        s += __shfl_xor(s, 8);  s += __shfl_xor(s, 16); s += __shfl_xor(s, 32);
        if ((t & 63) == 0) sbuf[t >> 6] = s;
        __syncthreads();
        float tot = sbuf[0] + sbuf[1] + sbuf[2] + sbuf[3];
        float rn = 1.f / fmaxf(sqrtf(tot), 1e-12f);
        unsigned short* fnb = (unsigned short*)(ws + OFF_FNB) + (size_t)b * D;
        unsigned short* afb = (unsigned short*)(ws + OFF_AFB) + (size_t)b * D;
        u16x8 on, oa;
        on[0]=f2b(f1.x*rn); on[1]=f2b(f1.y*rn); on[2]=f2b(f1.z*rn); on[3]=f2b(f1.w*rn);
        on[4]=f2b(f2.x*rn); on[5]=f2b(f2.y*rn); on[6]=f2b(f2.z*rn); on[7]=f2b(f2.w*rn);
        oa[0]=f2b(f1.x); oa[1]=f2b(f1.y); oa[2]=f2b(f1.z); oa[3]=f2b(f1.w);
        oa[4]=f2b(f2.x); oa[5]=f2b(f2.y); oa[6]=f2b(f2.z); oa[7]=f2b(f2.w);
        *(u16x8*)(fnb + i0) = on;
        *(u16x8*)(afb + i0) = oa;
    } else if (bid < 757) {
        int n0 = (bid - 245) * 2;
        unsigned short* dst = (unsigned short*)(ws + OFF_EMBB);
        int i0 = t * 8;
        for (int r = 0; r < 2; ++r) {
            const float* src = emb + (size_t)(n0 + r) * D;
            float4 f1 = *(const float4*)(src + i0);
            float4 f2 = *(const float4*)(src + i0 + 4);
            u16x8 o;
            o[0]=f2b(f1.x); o[1]=f2b(f1.y); o[2]=f2b(f1.z); o[3]=f2b(f1.w);
            o[4]=f2b(f2.x); o[5]=f2b(f2.y); o[6]=f2b(f2.z); o[7]=f2b(f2.w);
            *(u16x8*)(dst + (size_t)(n0 + r)*D + i0) = o;
        }
    } else {
        int rb = bid - 757;
        float (*tile)[33] = (float(*)[33])sbuf;
        int k0 = (rb >> 2) * 128, h0 = (rb & 3) * 32;
        int hh = t & 31, kk = t >> 5;
        for (int r = 0; r < 16; ++r)
            tile[kk + r*8][hh] = head_w1[(size_t)(k0 + kk + r*8)*HD + h0 + hh];
        __syncthreads();
        unsigned short* dst = (unsigned short*)(ws + OFF_W1T);
        int kcol = (t & 63) * 2, hrow = t >> 6;
        for (int r = 0; r < 8; ++r) {
            int h = hrow + r*4;
            u16x2 v;
            v[0] = f2b(tile[kcol][h]);
            v[1] = f2b(tile[kcol + 1][h]);
            *(u16x2*)(dst + (size_t)(h0 + h)*D + k0 + kcol) = v;
        }
    }
}

// ===================== K2: MFMA phase (512 thr, 243 blocks) =====================
// [0,128) attn ks=8 | [128,196) headzf K-split partials | [196,241) Wc | [241,243) px + zero out
__global__ void __launch_bounds__(512) k_main(const float* __restrict__ clf_b,
                                              float* __restrict__ ws,
                                              float* __restrict__ out) {
    __shared__ float part[2][32][128];
    __shared__ float wcp[8][16][16];
    int bid = blockIdx.x, t = threadIdx.x;
    int lane = t & 63, wv = t >> 6;
    int row16 = lane & 15, kgrp = lane >> 4;
    if (bid < 128) {
        const unsigned short* fnb  = (const unsigned short*)(ws + OFF_FNB);
        const unsigned short* embb = (const unsigned short*)(ws + OFF_EMBB);
        int nt = bid & 15, ks = bid >> 4;
        int b0 = (wv & 3) * 16;
        int n0 = nt*64 + (wv >> 2) * 32;
        const unsigned short* Ap = fnb  + (size_t)(b0 + row16)*D + ks*256 + kgrp*8;
        const unsigned short* B0 = embb + (size_t)(n0 + row16)*D + ks*256 + kgrp*8;
        const unsigned short* B1 = B0 + 16*D;
        f32x4 a0 = {0,0,0,0}, a1 = {0,0,0,0};
        #pragma unroll
        for (int s = 0; s < 8; ++s) {
            bf16x8 a = *(const bf16x8*)(Ap + s*32);
            a0 = __builtin_amdgcn_mfma_f32_16x16x32_bf16(a, *(const bf16x8*)(B0 + s*32), a0, 0, 0, 0);
            a1 = __builtin_amdgcn_mfma_f32_16x16x32_bf16(a, *(const bf16x8*)(B1 + s*32), a1, 0, 0, 0);
        }
        float* Sp = ws + OFF_SP + (size_t)ks * BSZ * NQ;
        #pragma unroll
        for (int r = 0; r < 4; ++r) {
            float* rowp = Sp + (size_t)(b0 + kgrp*4 + r)*NQ + n0;
            rowp[row16]      = a0[r];
            rowp[16 + row16] = a1[r];
        }
    } else if (bid < 196) {
        // ---- headzf K-split partials: role = (tile 0..33) x (kh 0..1) ----
        int role = bid - 128;
        int tile = role >> 1, kh = role & 1;
        bool isF = tile >= 32;
        const unsigned short* Arow = isF
            ? (const unsigned short*)(ws + OFF_AFB) + (size_t)(tile - 32) * 32 * D
            : (const unsigned short*)(ws + OFF_EMBB) + (size_t)tile * 32 * D;
        const unsigned short* w1t = (const unsigned short*)(ws + OFF_W1T);
        int hgrp = wv & 3, kq = wv >> 2;
        int koff = kh*1024 + kq*512;
        const unsigned short* Ap = Arow + (size_t)row16*D + koff + kgrp*8;
        const unsigned short* B0 = w1t + (size_t)(hgrp*32 + row16)*D + koff + kgrp*8;
        const unsigned short* B1 = B0 + 16*D;
        f32x4 h00 = {0,0,0,0}, h01 = {0,0,0,0}, h10 = {0,0,0,0}, h11 = {0,0,0,0};
        #pragma unroll 4
        for (int s = 0; s < 16; ++s) {
            bf16x8 a0 = *(const bf16x8*)(Ap + s*32);
            bf16x8 a1 = *(const bf16x8*)(Ap + 16*D + s*32);
            bf16x8 b0 = *(const bf16x8*)(B0 + s*32);
            bf16x8 b1 = *(const bf16x8*)(B1 + s*32);
            h00 = __builtin_amdgcn_mfma_f32_16x16x32_bf16(a0, b0, h00, 0, 0, 0);
            h01 = __builtin_amdgcn_mfma_f32_16x16x32_bf16(a0, b1, h01, 0, 0, 0);
            h10 = __builtin_amdgcn_mfma_f32_16x16x32_bf16(a1, b0, h10, 0, 0, 0);
            h11 = __builtin_amdgcn_mfma_f32_16x16x32_bf16(a1, b1, h11, 0, 0, 0);
        }
        int mb = kgrp*4, hc0 = hgrp*32 + row16, hc1 = hc0 + 16;
        #pragma unroll
        for (int r = 0; r < 4; ++r) {
            part[kq][mb + r][hc0]      = h00[r];
            part[kq][mb + r][hc1]      = h01[r];
            part[kq][16 + mb + r][hc0] = h10[r];
            part[kq][16 + mb + r][hc1] = h11[r];
        }
        __syncthreads();
        int row = t >> 4, c8 = (t & 15) * 8;
        float* dst = ws + OFF_H1P + (size_t)kh*1088*HD + (size_t)(tile*32 + row)*HD + c8;
        float4 o0, o1;
        o0.x = part[0][row][c8+0] + part[1][row][c8+0];
        o0.y = part[0][row][c8+1] + part[1][row][c8+1];
        o0.z = part[0][row][c8+2] + part[1][row][c8+2];
        o0.w = part[0][row][c8+3] + part[1][row][c8+3];
        o1.x = part[0][row][c8+4] + part[1][row][c8+4];
        o1.y = part[0][row][c8+5] + part[1][row][c8+5];
        o1.z = part[0][row][c8+6] + part[1][row][c8+6];
        o1.w = part[0][row][c8+7] + part[1][row][c8+7];
        *(float4*)dst = o0;
        *(float4*)(dst + 4) = o1;
    } else if (bid < 241) {
        // ---- Wc GEMM: one (mt,ntile) tile per block, K split across 8 waves ----
        int w = bid - 196;
        int mt = w / 5, ntile = w % 5;
        const unsigned short* mw2b = (const unsigned short*)(ws + OFF_MW2B);
        const unsigned short* cwt  = (const unsigned short*)(ws + OFF_CWT);
        const unsigned short* Ap = mw2b + (size_t)(mt*16 + row16)*D + wv*256 + kgrp*8;
        const unsigned short* Bp = cwt  + (size_t)(ntile*16 + row16)*D + wv*256 + kgrp*8;
        f32x4 acc = {0,0,0,0};
        #pragma unroll
        for (int s = 0; s < 8; ++s)
            acc = __builtin_amdgcn_mfma_f32_16x16x32_bf16(
                *(const bf16x8*)(Ap + s*32), *(const bf16x8*)(Bp + s*32), acc, 0, 0, 0);
        #pragma unroll
        for (int r = 0; r < 4; ++r)
            wcp[wv][kgrp*4 + r][row16] = acc[r];
        __syncthreads();
        if (t < 256) {
            int j = t >> 4, c16 = t & 15;
            float s = 0.f;
            #pragma unroll
            for (int q = 0; q < 8; ++q) s += wcp[q][j][c16];
            int jj = mt*16 + j, c = ntile*16 + c16;
            unsigned short* wct = (unsigned short*)(ws + OFF_WC);
            if (jj < HD)       wct[(size_t)c*HD + jj] = f2b(s);
            else if (jj == HD) ws[OFF_BVEC + c] = (c < NC) ? s + clf_b[c] : -1e30f;
        }
    } else {
        // ---- px partials + zero out ----
        int pb = bid - 241;
        for (int i = t; i < 2080; i += 512) out[pb*2080 + i] = 0.f;
        const unsigned short* fnb = (const unsigned short*)(ws + OFF_FNB);
        int bq = wv & 3, kq = (wv >> 2) + pb*2;
        int b0 = bq*16;
        const unsigned short* Ap = fnb + (size_t)(b0 + row16)*D + kq*512 + kgrp*8;
        const unsigned short* Bp = fnb + (size_t)row16*D + kq*512 + kgrp*8;
        f32x4 acc[4];
        #pragma unroll
        for (int nt = 0; nt < 4; ++nt) acc[nt] = (f32x4){0.f,0.f,0.f,0.f};
        #pragma unroll 2
        for (int s = 0; s < 16; ++s) {
            bf16x8 a = *(const bf16x8*)(Ap + s*32);
            #pragma unroll
            for (int nt = 0; nt < 4; ++nt)
                acc[nt] = __builtin_amdgcn_mfma_f32_16x16x32_bf16(
                    a, *(const bf16x8*)(Bp + (size_t)nt*16*D + s*32), acc[nt], 0, 0, 0);
        }
        #pragma unroll
        for (int r = 0; r < 4; ++r) {
            float v = acc[0][r] + acc[1][r] + acc[2][r] + acc[3][r];
            v += __shfl_xor(v, 1); v += __shfl_xor(v, 2);
            v += __shfl_xor(v, 4); v += __shfl_xor(v, 8);
            if (row16 == 0)
                ws[OFF_PXP + kq*64 + b0 + kgrp*4 + r] = v;
        }
    }
}

// ===================== K3: headzf finish + z_x softmax (98 blocks x 512) ===========
// [0,34) H1 reduce + BN/relu + W2 -> B2/A2T | [34,98) z_x softmax -> ZT[n][b]
__global__ void __launch_bounds__(512) k_finish(float* __restrict__ ws) {
    __shared__ unsigned short ush[32][136];
    __shared__ float red8m[8], red8s[8];
    int bid = blockIdx.x, t = threadIdx.x;
    int lane = t & 63, wv = t >> 6;
    int row16 = lane & 15, kgrp = lane >> 4;
    if (bid < 34) {
        int tile = bid;
        bool isF = tile >= 32;
        int row = t >> 4, c8 = (t & 15) * 8;
        const float* h0p = ws + OFF_H1P + (size_t)(tile*32 + row)*HD + c8;
        const float* h1p = h0p + (size_t)1088*HD;
        #pragma unroll
        for (int j = 0; j < 8; ++j) {
            int col = c8 + j;
            float v = h0p[j] + h1p[j];
            ush[row][col] = f2b(fmaxf(fmaf(v, ws[OFF_SCALEH + col], ws[OFF_CH + col]), 0.f));
        }
        __syncthreads();
        int rt = wv >> 2, wv2 = wv & 3;
        const unsigned short* wt = (const unsigned short*)(ws + (isF ? OFF_WAT : OFF_WZT));
        const unsigned short* W0 = wt + (size_t)(wv2*32 + row16)*HD + kgrp*8;
        const unsigned short* W1b = W0 + 16*HD;
        f32x4 o0 = {0,0,0,0}, o1 = {0,0,0,0};
        #pragma unroll
        for (int s = 0; s < 4; ++s) {
            bf16x8 a = *(const bf16x8*)(&ush[rt*16 + row16][s*32 + kgrp*8]);
            o0 = __builtin_amdgcn_mfma_f32_16x16x32_bf16(a, *(const bf16x8*)(W0 + s*32), o0, 0, 0, 0);
            o1 = __builtin_amdgcn_mfma_f32_16x16x32_bf16(a, *(const bf16x8*)(W1b + s*32), o1, 0, 0, 0);
        }
        int hcA = wv2*32 + row16, hcB = hcA + 16;
        int boff = isF ? OFF_BAC : OFF_BZC;
        float bz0 = ws[boff + hcA], bz1 = ws[boff + hcB];
        float* outp = isF ? (ws + OFF_A2T + (size_t)(tile - 32)*32*HD)
                          : (ws + OFF_B2  + (size_t)tile*32*HD);
        int mb = kgrp*4;
        #pragma unroll
        for (int r = 0; r < 4; ++r) {
            outp[(size_t)(rt*16 + mb + r)*HD + hcA] = o0[r] + bz0;
            outp[(size_t)(rt*16 + mb + r)*HD + hcB] = o1[r] + bz1;
        }
    } else {
        // ---- z_x softmax for batch row b -> ZT ----
        int b = bid - 34;
        const float invTS = 1.0f / (0.07f * 32.0f);
        const float* Sp = ws + OFF_SP + (size_t)b * NQ;
        float v0, v1;
        {
            float s = 0.f;
            #pragma unroll
            for (int p = 0; p < 8; ++p) s += Sp[(size_t)p*BSZ*NQ + t];
            v0 = s * invTS;
            s = 0.f;
            #pragma unroll
            for (int p = 0; p < 8; ++p) s += Sp[(size_t)p*BSZ*NQ + 512 + t];
            v1 = s * invTS;
        }
        float vmax = fmaxf(v0, v1);
        vmax = fmaxf(vmax, __shfl_xor(vmax, 1));  vmax = fmaxf(vmax, __shfl_xor(vmax, 2));
        vmax = fmaxf(vmax, __shfl_xor(vmax, 4));  vmax = fmaxf(vmax, __shfl_xor(vmax, 8));
        vmax = fmaxf(vmax, __shfl_xor(vmax, 16)); vmax = fmaxf(vmax, __shfl_xor(vmax, 32));
        if (lane == 0) red8m[wv] = vmax;
        __syncthreads();
        float m = red8m[0];
        #pragma unroll
        for (int q = 1; q < 8; ++q) m = fmaxf(m, red8m[q]);
        float e0 = __expf(v0 - m), e1 = __expf(v1 - m);
        float ss = e0 + e1;
        ss += __shfl_xor(ss, 1);  ss += __shfl_xor(ss, 2);  ss += __shfl_xor(ss, 4);
        ss += __shfl_xor(ss, 8);  ss += __shfl_xor(ss, 16); ss += __shfl_xor(ss, 32);
        if (lane == 0) red8s[wv] = ss;
        __syncthreads();
        float S = red8s[0] + red8s[1] + red8s[2] + red8s[3]
                + red8s[4] + red8s[5] + red8s[6] + red8s[7];
        float inv = 1.f / S;
        ws[OFF_ZT + (size_t)t*64 + b]         = e0 * inv;
        ws[OFF_ZT + (size_t)(512 + t)*64 + b] = e1 * inv;
    }
}

// ===================== K4: mixer+clf+softmax + fused out accumulation ==============
// 256 blocks x 512 thr, 4 n each. A2 rows in regs (n-invariant); per-n sum_x kept
// in LDS; out contribution z[b][n]*sumx[n][c] accumulated in regs, atomicAdd once.
__global__ void __launch_bounds__(512) k_mixout(const float* __restrict__ ws,
                                                float* __restrict__ out) {
    __shared__ unsigned short wcs[80][136];
    __shared__ float redp[8][80];
    __shared__ float sumxs[2][80];
    int bid = blockIdx.x, t = threadIdx.x;
    int lane = t & 63, wv = t >> 6;
    int row16 = lane & 15, kgrp = lane >> 4;
    // stage WcT
    const unsigned short* wct = (const unsigned short*)(ws + OFF_WC);
    for (int i = t; i < 80*16; i += 512) {
        int r = i >> 4, cc = (i & 15) * 8;
        *(u16x8*)&wcs[r][cc] = *(const u16x8*)(wct + (size_t)r*HD + cc);
    }
    // p_x from partials (redundant per wave, cheap)
    const float invTS = 1.0f / (0.07f * 8.0f);
    float sv = (ws[OFF_PXP + lane] + ws[OFF_PXP + 64 + lane]
              + ws[OFF_PXP + 128 + lane] + ws[OFF_PXP + 192 + lane]) * invTS;
    float m2 = sv;
    m2 = fmaxf(m2, __shfl_xor(m2, 1));  m2 = fmaxf(m2, __shfl_xor(m2, 2));
    m2 = fmaxf(m2, __shfl_xor(m2, 4));  m2 = fmaxf(m2, __shfl_xor(m2, 8));
    m2 = fmaxf(m2, __shfl_xor(m2, 16)); m2 = fmaxf(m2, __shfl_xor(m2, 32));
    float e2 = __expf(sv - m2);
    float ssum = e2;
    ssum += __shfl_xor(ssum, 1);  ssum += __shfl_xor(ssum, 2);  ssum += __shfl_xor(ssum, 4);
    ssum += __shfl_xor(ssum, 8);  ssum += __shfl_xor(ssum, 16); ssum += __shfl_xor(ssum, 32);
    float px = e2 / ssum;
    float bvl[5];
    #pragma unroll
    for (int ct = 0; ct < 5; ++ct) bvl[ct] = ws[OFF_BVEC + ct*16 + row16];
    // A2 rows to regs (fixed per wave, reused for all n)
    int bt = wv & 3, ng = wv >> 2;
    const float* a2r = ws + OFF_A2T + (size_t)(bt*16 + row16) * HD;
    float4 a2lo[4], a2hi[4];
    #pragma unroll
    for (int kt = 0; kt < 4; ++kt) {
        a2lo[kt] = *(const float4*)(a2r + kt*32 + kgrp*8);
        a2hi[kt] = *(const float4*)(a2r + kt*32 + kgrp*8 + 4);
    }
    float acc10[10];
    #pragma unroll
    for (int i = 0; i < 10; ++i) acc10[i] = 0.f;
    __syncthreads();   // wcs ready
    #pragma unroll
    for (int pass = 0; pass < 2; ++pass) {
        int n = bid*4 + pass*2 + ng;
        const float* b2r = ws + OFF_B2 + (size_t)n * HD;
        bf16x8 af[4];
        #pragma unroll
        for (int kt = 0; kt < 4; ++kt) {
            float4 blo = *(const float4*)(b2r + kt*32 + kgrp*8);
            float4 bhi = *(const float4*)(b2r + kt*32 + kgrp*8 + 4);
            bf16x8 v;
            v[0] = (short)f2b(fmaxf(a2lo[kt].x + blo.x, 0.f));
            v[1] = (short)f2b(fmaxf(a2lo[kt].y + blo.y, 0.f));
            v[2] = (short)f2b(fmaxf(a2lo[kt].z + blo.z, 0.f));
            v[3] = (short)f2b(fmaxf(a2lo[kt].w + blo.w, 0.f));
            v[4] = (short)f2b(fmaxf(a2hi[kt].x + bhi.x, 0.f));
            v[5] = (short)f2b(fmaxf(a2hi[kt].y + bhi.y, 0.f));
            v[6] = (short)f2b(fmaxf(a2hi[kt].z + bhi.z, 0.f));
            v[7] = (short)f2b(fmaxf(a2hi[kt].w + bhi.w, 0.f));
            af[kt] = v;
        }
        f32x4 acc[5];
        #pragma unroll
        for (int ct = 0; ct < 5; ++ct) acc[ct] = (f32x4){0.f,0.f,0.f,0.f};
        #pragma unroll
        for (int ct = 0; ct < 5; ++ct)
            #pragma unroll
            for (int kt = 0; kt < 4; ++kt)
                acc[ct] = __builtin_amdgcn_mfma_f32_16x16x32_bf16(
                    af[kt], *(const bf16x8*)(&wcs[ct*16 + row16][kt*32 + kgrp*8]),
                    acc[ct], 0, 0, 0);
        float outp[5] = {0.f, 0.f, 0.f, 0.f, 0.f};
        #pragma unroll
        for (int r = 0; r < 4; ++r) {
            float v0 = acc[0][r] + bvl[0];
            float v1 = acc[1][r] + bvl[1];
            float v2 = acc[2][r] + bvl[2];
            float v3 = acc[3][r] + bvl[3];
            float v4 = acc[4][r] + bvl[4];
            float m = fmaxf(fmaxf(fmaxf(v0, v1), fmaxf(v2, v3)), v4);
            m = fmaxf(m, __shfl_xor(m, 1)); m = fmaxf(m, __shfl_xor(m, 2));
            m = fmaxf(m, __shfl_xor(m, 4)); m = fmaxf(m, __shfl_xor(m, 8));
            float e0 = __expf(v0 - m), e1 = __expf(v1 - m), e2v = __expf(v2 - m);
            float e3 = __expf(v3 - m), e4 = __expf(v4 - m);
            float s = e0 + e1 + e2v + e3 + e4;
            s += __shfl_xor(s, 1); s += __shfl_xor(s, 2);
            s += __shfl_xor(s, 4); s += __shfl_xor(s, 8);
            float pxr = __shfl(px, bt*16 + kgrp*4 + r);
            float scale = pxr / s;
            outp[0] = fmaf(e0, scale, outp[0]);
            outp[1] = fmaf(e1, scale, outp[1]);
            outp[2] = fmaf(e2v, scale, outp[2]);
            outp[3] = fmaf(e3, scale, outp[3]);
            outp[4] = fmaf(e4, scale, outp[4]);
        }
        #pragma unroll
        for (int ct = 0; ct < 5; ++ct) {
            float v = outp[ct];
            v += __shfl_xor(v, 16); v += __shfl_xor(v, 32);
            outp[ct] = v;
        }
        if (kgrp == 0) {
            #pragma unroll
            for (int ct = 0; ct < 5; ++ct) redp[wv][ct*16 + row16] = outp[ct];
        }
        __syncthreads();
        if (t < 160) {
            int half = (t >= 80) ? 1 : 0;
            int c = t - 80*half;
            sumxs[half][c] = redp[half*4 + 0][c] + redp[half*4 + 1][c]
                           + redp[half*4 + 2][c] + redp[half*4 + 3][c];
        }
        __syncthreads();
        // accumulate out contribution: wave wv owns classes [wv*10, wv*10+10)
        {
            int n0p = bid*4 + pass*2;
            float z0 = ws[OFF_ZT + (size_t)n0p*64 + lane];
            float z1 = ws[OFF_ZT + (size_t)(n0p + 1)*64 + lane];
            #pragma unroll
            for (int i = 0; i < 10; ++i) {
                int c = wv*10 + i;
                float s0 = sumxs[0][c], s1 = sumxs[1][c];
                acc10[i] = fmaf(z0, s0, acc10[i]);
                acc10[i] = fmaf(z1, s1, acc10[i]);
            }
        }
        __syncthreads();  // protect redp/sumxs before next pass
    }
    #pragma unroll
    for (int i = 0; i < 10; ++i) {
        int c = wv*10 + i;
        if (c < NC) atomicAdd(&out[lane*NC + c], acc10[i]);
    }
}

extern "C" void kernel_launch(void* const* d_in, const int* in_sizes, int n_in,
                              void* d_out, int out_size, void* d_ws, size_t ws_size,
                              hipStream_t stream) {
    const float* all_f    = (const float*)d_in[0];
    const float* emb      = (const float*)d_in[1];
    const float* head_w1  = (const float*)d_in[3];
    const float* head_b1  = (const float*)d_in[4];
    const float* head_g   = (const float*)d_in[5];
    const float* head_beta= (const float*)d_in[6];
    const float* head_rm  = (const float*)d_in[7];
    const float* head_rv  = (const float*)d_in[8];
    const float* head_w2  = (const float*)d_in[9];
    const float* head_b2  = (const float*)d_in[10];
    const float* mix_w1   = (const float*)d_in[11];
    const float* mix_b1   = (const float*)d_in[12];
    const float* mix_g    = (const float*)d_in[13];
    const float* mix_beta = (const float*)d_in[14];
    const float* mix_rm   = (const float*)d_in[15];
    const float* mix_rv   = (const float*)d_in[16];
    const float* mix_w2   = (const float*)d_in[17];
    const float* mix_b2   = (const float*)d_in[18];
    const float* clf_w    = (const float*)d_in[19];
    const float* clf_b    = (const float*)d_in[20];
    float* ws  = (float*)d_ws;
    float* out = (float*)d_out;

    hipLaunchKernelGGL(k_prep, dim3(821), dim3(256), 0, stream,
                       all_f, emb, head_w1, head_b1, head_g, head_beta, head_rm, head_rv,
                       head_w2, head_b2, mix_w1, mix_b1, mix_g, mix_beta, mix_rm, mix_rv,
                       mix_w2, mix_b2, clf_w, ws);
    hipLaunchKernelGGL(k_main,   dim3(243), dim3(512), 0, stream, clf_b, ws, out);
    hipLaunchKernelGGL(k_finish, dim3(98),  dim3(512), 0, stream, ws);
    hipLaunchKernelGGL(k_mixout, dim3(256), dim3(512), 0, stream, ws, out);
}

// Round 5
// 60.336 us; speedup vs baseline: 2.4812x; 2.4812x over previous
//
#include <hip/hip_runtime.h>
#include <hip/hip_bf16.h>
#include <math.h>

#define D   2048
#define NQ  1024
#define BSZ 64
#define NC  65
#define HD  128

// workspace offsets (floats)
#define OFF_SCALEH 0
#define OFF_CH     128
#define OFF_BZC    256
#define OFF_BAC    384
#define OFF_BVEC   512
#define OFF_PXP    640
#define OFF_WC     896
#define OFF_SP     145280
#define OFF_SUMX   669568
#define OFF_FNB    751488
#define OFF_AFB    817024
#define OFF_EMBB   882560
#define OFF_W1T    1931136
#define OFF_WZT    2062208
#define OFF_WAT    2070400
#define OFF_MW2B   2078592
#define OFF_CWT    2226048
#define OFF_H1P    2307968
// total 2586496 fl = 10.35 MB

typedef __attribute__((ext_vector_type(8))) short    bf16x8;
typedef __attribute__((ext_vector_type(4))) float    f32x4;
typedef __attribute__((ext_vector_type(8))) unsigned short u16x8;
typedef __attribute__((ext_vector_type(2))) unsigned short u16x2;

__device__ inline unsigned short f2b(float v) {
    __hip_bfloat16 h = __float2bfloat16(v);
    return __builtin_bit_cast(unsigned short, h);
}

// ===================== K1: prep (block-role dispatch, 256 thr) =====================
__global__ void __launch_bounds__(256) k_prep(const float* __restrict__ all_f,
                                              const float* __restrict__ emb,
                                              const float* __restrict__ head_w1,
                                              const float* __restrict__ head_b1,
                                              const float* __restrict__ head_g,
                                              const float* __restrict__ head_beta,
                                              const float* __restrict__ head_rm,
                                              const float* __restrict__ head_rv,
                                              const float* __restrict__ head_w2,
                                              const float* __restrict__ head_b2,
                                              const float* __restrict__ mix_w1,
                                              const float* __restrict__ mix_b1,
                                              const float* __restrict__ mix_g,
                                              const float* __restrict__ mix_beta,
                                              const float* __restrict__ mix_rm,
                                              const float* __restrict__ mix_rv,
                                              const float* __restrict__ mix_w2,
                                              const float* __restrict__ mix_b2,
                                              const float* __restrict__ clf_w,
                                              float* __restrict__ ws) {
    __shared__ float sbuf[128*66];
    int bid = blockIdx.x, t = threadIdx.x;
    if (bid == 0) {
        int h = t & 127, jq = t >> 7;
        float sb = 0.f, sa = 0.f;
        #pragma unroll 8
        for (int j = jq*64; j < jq*64 + 64; ++j) {
            float b2v = head_b2[j];
            sb = fmaf(b2v, mix_w1[(HD + j)*HD + h], sb);
            sa = fmaf(b2v, mix_w1[j*HD + h], sa);
        }
        sbuf[jq*256 + h]       = sb;
        sbuf[jq*256 + 128 + h] = sa;
        __syncthreads();
        if (jq == 0) {
            float s = head_g[h] * rsqrtf(head_rv[h] + 1e-5f);
            ws[OFF_SCALEH + h] = s;
            ws[OFF_CH + h] = (head_b1[h] - head_rm[h]) * s + head_beta[h];
            float ms = mix_g[h] * rsqrtf(mix_rv[h] + 1e-5f);
            float msh = mix_beta[h] - mix_rm[h] * ms;
            float sbT = sbuf[h] + sbuf[256 + h];
            float saT = sbuf[128 + h] + sbuf[256 + 128 + h];
            ws[OFF_BZC + h] = sbT * ms;
            ws[OFF_BAC + h] = fmaf(saT + mix_b1[h], ms, msh);
        }
    } else if (bid < 129) {
        int j = bid - 1;
        int h = t & 127, which = t >> 7;
        const float* M1 = mix_w1 + (which ? 0 : HD*HD);
        float ms = mix_g[h] * rsqrtf(mix_rv[h] + 1e-5f);
        float acc = 0.f;
        #pragma unroll 8
        for (int k = 0; k < HD; ++k)
            acc = fmaf(head_w2[j*HD + k], M1[k*HD + h], acc);
        unsigned short* dst = (unsigned short*)(ws + (which ? OFF_WAT : OFF_WZT));
        dst[h*HD + j] = f2b(acc * ms);
    } else if (bid < 165) {
        int r0 = (bid - 129) * 4;
        unsigned short* dst = (unsigned short*)(ws + OFF_MW2B);
        int i0 = t * 8;
        for (int rr = 0; rr < 4; ++rr) {
            int r = r0 + rr;
            u16x8 o;
            if (r < HD || r == HD) {
                const float* src = (r < HD) ? (mix_w2 + (size_t)r * D) : mix_b2;
                float4 f1 = *(const float4*)(src + i0);
                float4 f2 = *(const float4*)(src + i0 + 4);
                o[0]=f2b(f1.x); o[1]=f2b(f1.y); o[2]=f2b(f1.z); o[3]=f2b(f1.w);
                o[4]=f2b(f2.x); o[5]=f2b(f2.y); o[6]=f2b(f2.z); o[7]=f2b(f2.w);
            } else {
                o[0]=0;o[1]=0;o[2]=0;o[3]=0;o[4]=0;o[5]=0;o[6]=0;o[7]=0;
            }
            *(u16x8*)(dst + (size_t)r*D + i0) = o;
        }
    } else if (bid < 181) {
        int k0 = (bid - 165) * 128;
        float (*tile)[66] = (float(*)[66])sbuf;
        for (int i = t; i < 128*65; i += 256) {
            int r = i / 65;
            tile[r][i - 65*r] = clf_w[(size_t)k0*65 + i];
        }
        __syncthreads();
        unsigned short* cwt = (unsigned short*)(ws + OFF_CWT);
        for (int idx = t; idx < 80*16; idx += 256) {
            int c = idx >> 4, kq = idx & 15;
            u16x8 v;
            #pragma unroll
            for (int j = 0; j < 8; ++j)
                v[j] = (c < NC) ? f2b(tile[kq*8 + j][c]) : (unsigned short)0;
            *(u16x8*)(cwt + (size_t)c*D + k0 + kq*8) = v;
        }
    } else if (bid < 245) {
        int b = bid - 181;
        const float* src = all_f + (size_t)b * D;
        int i0 = t * 8;
        float4 f1 = *(const float4*)(src + i0);
        float4 f2 = *(const float4*)(src + i0 + 4);
        float s = f1.x*f1.x + f1.y*f1.y + f1.z*f1.z + f1.w*f1.w
                + f2.x*f2.x + f2.y*f2.y + f2.z*f2.z + f2.w*f2.w;
        s += __shfl_xor(s, 1);  s += __shfl_xor(s, 2);  s += __shfl_xor(s, 4);
        s += __shfl_xor(s, 8);  s += __shfl_xor(s, 16); s += __shfl_xor(s, 32);
        if ((t & 63) == 0) sbuf[t >> 6] = s;
        __syncthreads();
        float tot = sbuf[0] + sbuf[1] + sbuf[2] + sbuf[3];
        float rn = 1.f / fmaxf(sqrtf(tot), 1e-12f);
        unsigned short* fnb = (unsigned short*)(ws + OFF_FNB) + (size_t)b * D;
        unsigned short* afb = (unsigned short*)(ws + OFF_AFB) + (size_t)b * D;
        u16x8 on, oa;
        on[0]=f2b(f1.x*rn); on[1]=f2b(f1.y*rn); on[2]=f2b(f1.z*rn); on[3]=f2b(f1.w*rn);
        on[4]=f2b(f2.x*rn); on[5]=f2b(f2.y*rn); on[6]=f2b(f2.z*rn); on[7]=f2b(f2.w*rn);
        oa[0]=f2b(f1.x); oa[1]=f2b(f1.y); oa[2]=f2b(f1.z); oa[3]=f2b(f1.w);
        oa[4]=f2b(f2.x); oa[5]=f2b(f2.y); oa[6]=f2b(f2.z); oa[7]=f2b(f2.w);
        *(u16x8*)(fnb + i0) = on;
        *(u16x8*)(afb + i0) = oa;
    } else if (bid < 757) {
        int n0 = (bid - 245) * 2;
        unsigned short* dst = (unsigned short*)(ws + OFF_EMBB);
        int i0 = t * 8;
        for (int r = 0; r < 2; ++r) {
            const float* src = emb + (size_t)(n0 + r) * D;
            float4 f1 = *(const float4*)(src + i0);
            float4 f2 = *(const float4*)(src + i0 + 4);
            u16x8 o;
            o[0]=f2b(f1.x); o[1]=f2b(f1.y); o[2]=f2b(f1.z); o[3]=f2b(f1.w);
            o[4]=f2b(f2.x); o[5]=f2b(f2.y); o[6]=f2b(f2.z); o[7]=f2b(f2.w);
            *(u16x8*)(dst + (size_t)(n0 + r)*D + i0) = o;
        }
    } else {
        int rb = bid - 757;
        float (*tile)[33] = (float(*)[33])sbuf;
        int k0 = (rb >> 2) * 128, h0 = (rb & 3) * 32;
        int hh = t & 31, kk = t >> 5;
        for (int r = 0; r < 16; ++r)
            tile[kk + r*8][hh] = head_w1[(size_t)(k0 + kk + r*8)*HD + h0 + hh];
        __syncthreads();
        unsigned short* dst = (unsigned short*)(ws + OFF_W1T);
        int kcol = (t & 63) * 2, hrow = t >> 6;
        for (int r = 0; r < 8; ++r) {
            int h = hrow + r*4;
            u16x2 v;
            v[0] = f2b(tile[kcol][h]);
            v[1] = f2b(tile[kcol + 1][h]);
            *(u16x2*)(dst + (size_t)(h0 + h)*D + k0 + kcol) = v;
        }
    }
}

// ===================== K2: MFMA phase (512 thr, 243 blocks) =====================
// [0,128) attn ks=8 | [128,196) headzf K-split partials | [196,241) Wc | [241,243) px
__global__ void __launch_bounds__(512) k_main(const float* __restrict__ clf_b,
                                              float* __restrict__ ws) {
    __shared__ float part[2][32][128];
    __shared__ float wcp[8][16][16];
    int bid = blockIdx.x, t = threadIdx.x;
    int lane = t & 63, wv = t >> 6;
    int row16 = lane & 15, kgrp = lane >> 4;
    if (bid < 128) {
        const unsigned short* fnb  = (const unsigned short*)(ws + OFF_FNB);
        const unsigned short* embb = (const unsigned short*)(ws + OFF_EMBB);
        int nt = bid & 15, ks = bid >> 4;
        int b0 = (wv & 3) * 16;
        int n0 = nt*64 + (wv >> 2) * 32;
        const unsigned short* Ap = fnb  + (size_t)(b0 + row16)*D + ks*256 + kgrp*8;
        const unsigned short* B0 = embb + (size_t)(n0 + row16)*D + ks*256 + kgrp*8;
        const unsigned short* B1 = B0 + 16*D;
        f32x4 a0 = {0,0,0,0}, a1 = {0,0,0,0};
        #pragma unroll
        for (int s = 0; s < 8; ++s) {
            bf16x8 a = *(const bf16x8*)(Ap + s*32);
            a0 = __builtin_amdgcn_mfma_f32_16x16x32_bf16(a, *(const bf16x8*)(B0 + s*32), a0, 0, 0, 0);
            a1 = __builtin_amdgcn_mfma_f32_16x16x32_bf16(a, *(const bf16x8*)(B1 + s*32), a1, 0, 0, 0);
        }
        float* Sp = ws + OFF_SP + (size_t)ks * BSZ * NQ;
        #pragma unroll
        for (int r = 0; r < 4; ++r) {
            float* rowp = Sp + (size_t)(b0 + kgrp*4 + r)*NQ + n0;
            rowp[row16]      = a0[r];
            rowp[16 + row16] = a1[r];
        }
    } else if (bid < 196) {
        // ---- headzf K-split partials: role = (tile 0..33) x (kh 0..1) ----
        int role = bid - 128;
        int tile = role >> 1, kh = role & 1;
        bool isF = tile >= 32;
        const unsigned short* Arow = isF
            ? (const unsigned short*)(ws + OFF_AFB) + (size_t)(tile - 32) * 32 * D
            : (const unsigned short*)(ws + OFF_EMBB) + (size_t)tile * 32 * D;
        const unsigned short* w1t = (const unsigned short*)(ws + OFF_W1T);
        int hgrp = wv & 3, kq = wv >> 2;
        int koff = kh*1024 + kq*512;
        const unsigned short* Ap = Arow + (size_t)row16*D + koff + kgrp*8;
        const unsigned short* B0 = w1t + (size_t)(hgrp*32 + row16)*D + koff + kgrp*8;
        const unsigned short* B1 = B0 + 16*D;
        f32x4 h00 = {0,0,0,0}, h01 = {0,0,0,0}, h10 = {0,0,0,0}, h11 = {0,0,0,0};
        #pragma unroll 4
        for (int s = 0; s < 16; ++s) {
            bf16x8 a0 = *(const bf16x8*)(Ap + s*32);
            bf16x8 a1 = *(const bf16x8*)(Ap + 16*D + s*32);
            bf16x8 b0 = *(const bf16x8*)(B0 + s*32);
            bf16x8 b1 = *(const bf16x8*)(B1 + s*32);
            h00 = __builtin_amdgcn_mfma_f32_16x16x32_bf16(a0, b0, h00, 0, 0, 0);
            h01 = __builtin_amdgcn_mfma_f32_16x16x32_bf16(a0, b1, h01, 0, 0, 0);
            h10 = __builtin_amdgcn_mfma_f32_16x16x32_bf16(a1, b0, h10, 0, 0, 0);
            h11 = __builtin_amdgcn_mfma_f32_16x16x32_bf16(a1, b1, h11, 0, 0, 0);
        }
        int mb = kgrp*4, hc0 = hgrp*32 + row16, hc1 = hc0 + 16;
        #pragma unroll
        for (int r = 0; r < 4; ++r) {
            part[kq][mb + r][hc0]      = h00[r];
            part[kq][mb + r][hc1]      = h01[r];
            part[kq][16 + mb + r][hc0] = h10[r];
            part[kq][16 + mb + r][hc1] = h11[r];
        }
        __syncthreads();
        int row = t >> 4, c8 = (t & 15) * 8;
        float* dst = ws + OFF_H1P + (size_t)kh*1088*HD + (size_t)(tile*32 + row)*HD + c8;
        float4 o0, o1;
        o0.x = part[0][row][c8+0] + part[1][row][c8+0];
        o0.y = part[0][row][c8+1] + part[1][row][c8+1];
        o0.z = part[0][row][c8+2] + part[1][row][c8+2];
        o0.w = part[0][row][c8+3] + part[1][row][c8+3];
        o1.x = part[0][row][c8+4] + part[1][row][c8+4];
        o1.y = part[0][row][c8+5] + part[1][row][c8+5];
        o1.z = part[0][row][c8+6] + part[1][row][c8+6];
        o1.w = part[0][row][c8+7] + part[1][row][c8+7];
        *(float4*)dst = o0;
        *(float4*)(dst + 4) = o1;
    } else if (bid < 241) {
        // ---- Wc GEMM ----
        int w = bid - 196;
        int mt = w / 5, ntile = w % 5;
        const unsigned short* mw2b = (const unsigned short*)(ws + OFF_MW2B);
        const unsigned short* cwt  = (const unsigned short*)(ws + OFF_CWT);
        const unsigned short* Ap = mw2b + (size_t)(mt*16 + row16)*D + wv*256 + kgrp*8;
        const unsigned short* Bp = cwt  + (size_t)(ntile*16 + row16)*D + wv*256 + kgrp*8;
        f32x4 acc = {0,0,0,0};
        #pragma unroll
        for (int s = 0; s < 8; ++s)
            acc = __builtin_amdgcn_mfma_f32_16x16x32_bf16(
                *(const bf16x8*)(Ap + s*32), *(const bf16x8*)(Bp + s*32), acc, 0, 0, 0);
        #pragma unroll
        for (int r = 0; r < 4; ++r)
            wcp[wv][kgrp*4 + r][row16] = acc[r];
        __syncthreads();
        if (t < 256) {
            int j = t >> 4, c16 = t & 15;
            float s = 0.f;
            #pragma unroll
            for (int q = 0; q < 8; ++q) s += wcp[q][j][c16];
            int jj = mt*16 + j, c = ntile*16 + c16;
            unsigned short* wct = (unsigned short*)(ws + OFF_WC);
            if (jj < HD)       wct[(size_t)c*HD + jj] = f2b(s);
            else if (jj == HD) ws[OFF_BVEC + c] = (c < NC) ? s + clf_b[c] : -1e30f;
        }
    } else {
        // ---- px partials ----
        int pb = bid - 241;
        const unsigned short* fnb = (const unsigned short*)(ws + OFF_FNB);
        int bq = wv & 3, kq = (wv >> 2) + pb*2;
        int b0 = bq*16;
        const unsigned short* Ap = fnb + (size_t)(b0 + row16)*D + kq*512 + kgrp*8;
        const unsigned short* Bp = fnb + (size_t)row16*D + kq*512 + kgrp*8;
        f32x4 acc[4];
        #pragma unroll
        for (int nt = 0; nt < 4; ++nt) acc[nt] = (f32x4){0.f,0.f,0.f,0.f};
        #pragma unroll 2
        for (int s = 0; s < 16; ++s) {
            bf16x8 a = *(const bf16x8*)(Ap + s*32);
            #pragma unroll
            for (int nt = 0; nt < 4; ++nt)
                acc[nt] = __builtin_amdgcn_mfma_f32_16x16x32_bf16(
                    a, *(const bf16x8*)(Bp + (size_t)nt*16*D + s*32), acc[nt], 0, 0, 0);
        }
        #pragma unroll
        for (int r = 0; r < 4; ++r) {
            float v = acc[0][r] + acc[1][r] + acc[2][r] + acc[3][r];
            v += __shfl_xor(v, 1); v += __shfl_xor(v, 2);
            v += __shfl_xor(v, 4); v += __shfl_xor(v, 8);
            if (row16 == 0)
                ws[OFF_PXP + kq*64 + b0 + kgrp*4 + r] = v;
        }
    }
}

// ===================== K3: per-block headzf finish (LDS) + mixer + SUMX ============
// 256 blocks x 512 thr, 4 n each. Each block finishes its own B2 tile (32 rows)
// and both A2 tiles (64 rows) into LDS from H1P partials, then runs the mixer.
__global__ void __launch_bounds__(512) k_mixfin(const float* __restrict__ ws,
                                                float* __restrict__ wsw) {
    __shared__ unsigned short wcs[80][136];
    __shared__ unsigned short ush[32][136];
    __shared__ float a2s[64][132];
    __shared__ float b2s[32][132];
    __shared__ float redp[8][80];
    __shared__ float sumxs[2][80];
    int bid = blockIdx.x, t = threadIdx.x;
    int lane = t & 63, wv = t >> 6;
    int row16 = lane & 15, kgrp = lane >> 4;

    // stage WcT
    const unsigned short* wct = (const unsigned short*)(ws + OFF_WC);
    for (int i = t; i < 80*16; i += 512) {
        int r = i >> 4, cc = (i & 15) * 8;
        *(u16x8*)&wcs[r][cc] = *(const u16x8*)(wct + (size_t)r*HD + cc);
    }

    // ---- finish helper (inlined 3x): tile -> LDS dest ----
    int frow = t >> 4, fc8 = (t & 15) * 8;
    int rt = wv >> 2, wv2 = wv & 3;
    int hcA = wv2*32 + row16, hcB = hcA + 16;
    int mb = kgrp*4;
    #pragma unroll
    for (int ft = 0; ft < 3; ++ft) {
        int tile = (ft == 0) ? (bid >> 3) : (31 + ft);   // B2 tile, then A2 tiles 32,33
        bool isF = (ft != 0);
        const float* h0p = ws + OFF_H1P + (size_t)(tile*32 + frow)*HD + fc8;
        const float* h1p = h0p + (size_t)1088*HD;
        if (ft) __syncthreads();   // ush reuse hazard
        #pragma unroll
        for (int j = 0; j < 8; ++j) {
            int col = fc8 + j;
            float v = h0p[j] + h1p[j];
            ush[frow][col] = f2b(fmaxf(fmaf(v, ws[OFF_SCALEH + col], ws[OFF_CH + col]), 0.f));
        }
        __syncthreads();
        const unsigned short* wt = (const unsigned short*)(ws + (isF ? OFF_WAT : OFF_WZT));
        const unsigned short* W0 = wt + (size_t)(wv2*32 + row16)*HD + kgrp*8;
        const unsigned short* W1b = W0 + 16*HD;
        f32x4 o0 = {0,0,0,0}, o1 = {0,0,0,0};
        #pragma unroll
        for (int s = 0; s < 4; ++s) {
            bf16x8 a = *(const bf16x8*)(&ush[rt*16 + row16][s*32 + kgrp*8]);
            o0 = __builtin_amdgcn_mfma_f32_16x16x32_bf16(a, *(const bf16x8*)(W0 + s*32), o0, 0, 0, 0);
            o1 = __builtin_amdgcn_mfma_f32_16x16x32_bf16(a, *(const bf16x8*)(W1b + s*32), o1, 0, 0, 0);
        }
        int boff = isF ? OFF_BAC : OFF_BZC;
        float bz0 = ws[boff + hcA], bz1 = ws[boff + hcB];
        #pragma unroll
        for (int r = 0; r < 4; ++r) {
            int orow = rt*16 + mb + r;
            if (ft == 0) {
                b2s[orow][hcA] = o0[r] + bz0;
                b2s[orow][hcB] = o1[r] + bz1;
            } else {
                a2s[(ft-1)*32 + orow][hcA] = o0[r] + bz0;
                a2s[(ft-1)*32 + orow][hcB] = o1[r] + bz1;
            }
        }
    }

    // p_x from partials
    const float invTS = 1.0f / (0.07f * 8.0f);
    float sv = (ws[OFF_PXP + lane] + ws[OFF_PXP + 64 + lane]
              + ws[OFF_PXP + 128 + lane] + ws[OFF_PXP + 192 + lane]) * invTS;
    float m2 = sv;
    m2 = fmaxf(m2, __shfl_xor(m2, 1));  m2 = fmaxf(m2, __shfl_xor(m2, 2));
    m2 = fmaxf(m2, __shfl_xor(m2, 4));  m2 = fmaxf(m2, __shfl_xor(m2, 8));
    m2 = fmaxf(m2, __shfl_xor(m2, 16)); m2 = fmaxf(m2, __shfl_xor(m2, 32));
    float e2 = __expf(sv - m2);
    float ssum = e2;
    ssum += __shfl_xor(ssum, 1);  ssum += __shfl_xor(ssum, 2);  ssum += __shfl_xor(ssum, 4);
    ssum += __shfl_xor(ssum, 8);  ssum += __shfl_xor(ssum, 16); ssum += __shfl_xor(ssum, 32);
    float px = e2 / ssum;
    float bvl[5];
    #pragma unroll
    for (int ct = 0; ct < 5; ++ct) bvl[ct] = ws[OFF_BVEC + ct*16 + row16];
    __syncthreads();   // a2s/b2s/wcs ready

    // A2 rows to regs (fixed per wave, reused for all n)
    int bt = wv & 3, ng = wv >> 2;
    float4 a2lo[4], a2hi[4];
    #pragma unroll
    for (int kt = 0; kt < 4; ++kt) {
        a2lo[kt] = *(const float4*)(&a2s[bt*16 + row16][kt*32 + kgrp*8]);
        a2hi[kt] = *(const float4*)(&a2s[bt*16 + row16][kt*32 + kgrp*8 + 4]);
    }
    int r0 = (bid & 7) * 4;   // base row within b2s for n = bid*4
    #pragma unroll
    for (int pass = 0; pass < 2; ++pass) {
        const float* b2r = &b2s[r0 + pass*2 + ng][0];
        bf16x8 af[4];
        #pragma unroll
        for (int kt = 0; kt < 4; ++kt) {
            float4 blo = *(const float4*)(b2r + kt*32 + kgrp*8);
            float4 bhi = *(const float4*)(b2r + kt*32 + kgrp*8 + 4);
            bf16x8 v;
            v[0] = (short)f2b(fmaxf(a2lo[kt].x + blo.x, 0.f));
            v[1] = (short)f2b(fmaxf(a2lo[kt].y + blo.y, 0.f));
            v[2] = (short)f2b(fmaxf(a2lo[kt].z + blo.z, 0.f));
            v[3] = (short)f2b(fmaxf(a2lo[kt].w + blo.w, 0.f));
            v[4] = (short)f2b(fmaxf(a2hi[kt].x + bhi.x, 0.f));
            v[5] = (short)f2b(fmaxf(a2hi[kt].y + bhi.y, 0.f));
            v[6] = (short)f2b(fmaxf(a2hi[kt].z + bhi.z, 0.f));
            v[7] = (short)f2b(fmaxf(a2hi[kt].w + bhi.w, 0.f));
            af[kt] = v;
        }
        f32x4 acc[5];
        #pragma unroll
        for (int ct = 0; ct < 5; ++ct) acc[ct] = (f32x4){0.f,0.f,0.f,0.f};
        #pragma unroll
        for (int ct = 0; ct < 5; ++ct)
            #pragma unroll
            for (int kt = 0; kt < 4; ++kt)
                acc[ct] = __builtin_amdgcn_mfma_f32_16x16x32_bf16(
                    af[kt], *(const bf16x8*)(&wcs[ct*16 + row16][kt*32 + kgrp*8]),
                    acc[ct], 0, 0, 0);
        float outp[5] = {0.f, 0.f, 0.f, 0.f, 0.f};
        #pragma unroll
        for (int r = 0; r < 4; ++r) {
            float v0 = acc[0][r] + bvl[0];
            float v1 = acc[1][r] + bvl[1];
            float v2 = acc[2][r] + bvl[2];
            float v3 = acc[3][r] + bvl[3];
            float v4 = acc[4][r] + bvl[4];
            float m = fmaxf(fmaxf(fmaxf(v0, v1), fmaxf(v2, v3)), v4);
            m = fmaxf(m, __shfl_xor(m, 1)); m = fmaxf(m, __shfl_xor(m, 2));
            m = fmaxf(m, __shfl_xor(m, 4)); m = fmaxf(m, __shfl_xor(m, 8));
            float e0 = __expf(v0 - m), e1 = __expf(v1 - m), e2v = __expf(v2 - m);
            float e3 = __expf(v3 - m), e4 = __expf(v4 - m);
            float s = e0 + e1 + e2v + e3 + e4;
            s += __shfl_xor(s, 1); s += __shfl_xor(s, 2);
            s += __shfl_xor(s, 4); s += __shfl_xor(s, 8);
            float pxr = __shfl(px, bt*16 + kgrp*4 + r);
            float scale = pxr / s;
            outp[0] = fmaf(e0, scale, outp[0]);
            outp[1] = fmaf(e1, scale, outp[1]);
            outp[2] = fmaf(e2v, scale, outp[2]);
            outp[3] = fmaf(e3, scale, outp[3]);
            outp[4] = fmaf(e4, scale, outp[4]);
        }
        #pragma unroll
        for (int ct = 0; ct < 5; ++ct) {
            float v = outp[ct];
            v += __shfl_xor(v, 16); v += __shfl_xor(v, 32);
            outp[ct] = v;
        }
        if (kgrp == 0) {
            #pragma unroll
            for (int ct = 0; ct < 5; ++ct) redp[wv][ct*16 + row16] = outp[ct];
        }
        __syncthreads();
        if (t < 160) {
            int half = (t >= 80) ? 1 : 0;
            int c = t - 80*half;
            int nn = bid*4 + pass*2 + half;
            wsw[OFF_SUMX + (size_t)nn*80 + c] =
                redp[half*4 + 0][c] + redp[half*4 + 1][c]
              + redp[half*4 + 2][c] + redp[half*4 + 3][c];
        }
        __syncthreads();
    }
}

// ===================== K4: z_x softmax fused with out = z_x @ sum_x ================
__global__ void __launch_bounds__(512) k_outz(const float* __restrict__ ws, float* __restrict__ out) {
    __shared__ float red8m[8], red8s[8];
    __shared__ float zrow[NQ];
    __shared__ float parts[8][128];
    int b = blockIdx.x, t = threadIdx.x;
    int lane = t & 63, wvv = t >> 6;
    const float invTS = 1.0f / (0.07f * 32.0f);
    const float* Sp = ws + OFF_SP + (size_t)b * NQ;
    float v0, v1;
    {
        float s = 0.f;
        #pragma unroll
        for (int p = 0; p < 8; ++p) s += Sp[(size_t)p*BSZ*NQ + t];
        v0 = s * invTS;
        s = 0.f;
        #pragma unroll
        for (int p = 0; p < 8; ++p) s += Sp[(size_t)p*BSZ*NQ + 512 + t];
        v1 = s * invTS;
    }
    float vmax = fmaxf(v0, v1);
    vmax = fmaxf(vmax, __shfl_xor(vmax, 1));  vmax = fmaxf(vmax, __shfl_xor(vmax, 2));
    vmax = fmaxf(vmax, __shfl_xor(vmax, 4));  vmax = fmaxf(vmax, __shfl_xor(vmax, 8));
    vmax = fmaxf(vmax, __shfl_xor(vmax, 16)); vmax = fmaxf(vmax, __shfl_xor(vmax, 32));
    if (lane == 0) red8m[wvv] = vmax;
    __syncthreads();
    float m = red8m[0];
    #pragma unroll
    for (int q = 1; q < 8; ++q) m = fmaxf(m, red8m[q]);
    float e0 = __expf(v0 - m), e1 = __expf(v1 - m);
    float ss = e0 + e1;
    ss += __shfl_xor(ss, 1);  ss += __shfl_xor(ss, 2);  ss += __shfl_xor(ss, 4);
    ss += __shfl_xor(ss, 8);  ss += __shfl_xor(ss, 16); ss += __shfl_xor(ss, 32);
    if (lane == 0) red8s[wvv] = ss;
    __syncthreads();
    float S = red8s[0] + red8s[1] + red8s[2] + red8s[3]
            + red8s[4] + red8s[5] + red8s[6] + red8s[7];
    float inv = 1.f / S;
    zrow[t]       = e0 * inv;
    zrow[512 + t] = e1 * inv;
    __syncthreads();
    const float* Sx = ws + OFF_SUMX;
    int c2 = 64 + (lane & 15);
    int nbase = wvv * 128;
    float a0 = 0.f, a1 = 0.f;
    #pragma unroll 8
    for (int k = 0; k < 128; ++k) {
        float z = zrow[nbase + k];
        const float* srow = Sx + (size_t)(nbase + k) * 80;
        a0 = fmaf(z, srow[lane], a0);
        a1 = fmaf(z, srow[c2], a1);
    }
    parts[wvv][lane] = a0;
    if (lane < 16) parts[wvv][64 + lane] = a1;
    __syncthreads();
    if (t < NC) {
        float s = 0.f;
        #pragma unroll
        for (int q = 0; q < 8; ++q) s += parts[q][t];
        out[b*NC + t] = s;
    }
}

extern "C" void kernel_launch(void* const* d_in, const int* in_sizes, int n_in,
                              void* d_out, int out_size, void* d_ws, size_t ws_size,
                              hipStream_t stream) {
    const float* all_f    = (const float*)d_in[0];
    const float* emb      = (const float*)d_in[1];
    const float* head_w1  = (const float*)d_in[3];
    const float* head_b1  = (const float*)d_in[4];
    const float* head_g   = (const float*)d_in[5];
    const float* head_beta= (const float*)d_in[6];
    const float* head_rm  = (const float*)d_in[7];
    const float* head_rv  = (const float*)d_in[8];
    const float* head_w2  = (const float*)d_in[9];
    const float* head_b2  = (const float*)d_in[10];
    const float* mix_w1   = (const float*)d_in[11];
    const float* mix_b1   = (const float*)d_in[12];
    const float* mix_g    = (const float*)d_in[13];
    const float* mix_beta = (const float*)d_in[14];
    const float* mix_rm   = (const float*)d_in[15];
    const float* mix_rv   = (const float*)d_in[16];
    const float* mix_w2   = (const float*)d_in[17];
    const float* mix_b2   = (const float*)d_in[18];
    const float* clf_w    = (const float*)d_in[19];
    const float* clf_b    = (const float*)d_in[20];
    float* ws  = (float*)d_ws;
    float* out = (float*)d_out;

    hipLaunchKernelGGL(k_prep, dim3(821), dim3(256), 0, stream,
                       all_f, emb, head_w1, head_b1, head_g, head_beta, head_rm, head_rv,
                       head_w2, head_b2, mix_w1, mix_b1, mix_g, mix_beta, mix_rm, mix_rv,
                       mix_w2, mix_b2, clf_w, ws);
    hipLaunchKernelGGL(k_main,   dim3(243), dim3(512), 0, stream, clf_b, ws);
    hipLaunchKernelGGL(k_mixfin, dim3(256), dim3(512), 0, stream, ws, ws);
    hipLaunchKernelGGL(k_outz,   dim3(64),  dim3(512), 0, stream, ws, out);
}

// Round 6
// 59.333 us; speedup vs baseline: 2.5232x; 1.0169x over previous
//
#include <hip/hip_runtime.h>
#include <hip/hip_bf16.h>
#include <math.h>

#define D   2048
#define NQ  1024
#define BSZ 64
#define NC  65
#define HD  128

// workspace offsets (floats)
#define OFF_SCALEH 0
#define OFF_CH     128
#define OFF_BZC    256
#define OFF_BAC    384
#define OFF_BVEC   512
#define OFF_PXP    640
#define OFF_WC     896
#define OFF_SP     145280
#define OFF_SUMX   669568
#define OFF_FNB    751488
#define OFF_AFB    817024
#define OFF_EMBB   882560
#define OFF_W1T    1931136
#define OFF_WZT    2062208
#define OFF_WAT    2070400
#define OFF_MW2B   2078592
#define OFF_CWT    2226048
#define OFF_H1P    2307968
// total 2586496 fl = 10.35 MB

typedef __attribute__((ext_vector_type(8))) short    bf16x8;
typedef __attribute__((ext_vector_type(4))) float    f32x4;
typedef __attribute__((ext_vector_type(8))) unsigned short u16x8;
typedef __attribute__((ext_vector_type(2))) unsigned short u16x2;

__device__ inline unsigned short f2b(float v) {
    __hip_bfloat16 h = __float2bfloat16(v);
    return __builtin_bit_cast(unsigned short, h);
}
__device__ inline float bf2f(unsigned short u) {
    return __builtin_bit_cast(float, ((unsigned)u) << 16);
}

// ===================== K1: prep (block-role dispatch, 256 thr) =====================
__global__ void __launch_bounds__(256) k_prep(const float* __restrict__ all_f,
                                              const float* __restrict__ emb,
                                              const float* __restrict__ head_w1,
                                              const float* __restrict__ head_b1,
                                              const float* __restrict__ head_g,
                                              const float* __restrict__ head_beta,
                                              const float* __restrict__ head_rm,
                                              const float* __restrict__ head_rv,
                                              const float* __restrict__ head_w2,
                                              const float* __restrict__ head_b2,
                                              const float* __restrict__ mix_w1,
                                              const float* __restrict__ mix_b1,
                                              const float* __restrict__ mix_g,
                                              const float* __restrict__ mix_beta,
                                              const float* __restrict__ mix_rm,
                                              const float* __restrict__ mix_rv,
                                              const float* __restrict__ mix_w2,
                                              const float* __restrict__ mix_b2,
                                              const float* __restrict__ clf_w,
                                              float* __restrict__ ws) {
    __shared__ float sbuf[128*66];
    int bid = blockIdx.x, t = threadIdx.x;
    if (bid == 0) {
        int h = t & 127, jq = t >> 7;
        float sb = 0.f, sa = 0.f;
        #pragma unroll 8
        for (int j = jq*64; j < jq*64 + 64; ++j) {
            float b2v = head_b2[j];
            sb = fmaf(b2v, mix_w1[(HD + j)*HD + h], sb);
            sa = fmaf(b2v, mix_w1[j*HD + h], sa);
        }
        sbuf[jq*256 + h]       = sb;
        sbuf[jq*256 + 128 + h] = sa;
        __syncthreads();
        if (jq == 0) {
            float s = head_g[h] * rsqrtf(head_rv[h] + 1e-5f);
            ws[OFF_SCALEH + h] = s;
            ws[OFF_CH + h] = (head_b1[h] - head_rm[h]) * s + head_beta[h];
            float ms = mix_g[h] * rsqrtf(mix_rv[h] + 1e-5f);
            float msh = mix_beta[h] - mix_rm[h] * ms;
            float sbT = sbuf[h] + sbuf[256 + h];
            float saT = sbuf[128 + h] + sbuf[256 + 128 + h];
            ws[OFF_BZC + h] = sbT * ms;
            ws[OFF_BAC + h] = fmaf(saT + mix_b1[h], ms, msh);
        }
    } else if (bid < 129) {
        int j = bid - 1;
        int h = t & 127, which = t >> 7;
        const float* M1 = mix_w1 + (which ? 0 : HD*HD);
        float ms = mix_g[h] * rsqrtf(mix_rv[h] + 1e-5f);
        float acc = 0.f;
        #pragma unroll 8
        for (int k = 0; k < HD; ++k)
            acc = fmaf(head_w2[j*HD + k], M1[k*HD + h], acc);
        unsigned short* dst = (unsigned short*)(ws + (which ? OFF_WAT : OFF_WZT));
        dst[h*HD + j] = f2b(acc * ms);
    } else if (bid < 165) {
        int r0 = (bid - 129) * 4;
        unsigned short* dst = (unsigned short*)(ws + OFF_MW2B);
        int i0 = t * 8;
        for (int rr = 0; rr < 4; ++rr) {
            int r = r0 + rr;
            u16x8 o;
            if (r < HD || r == HD) {
                const float* src = (r < HD) ? (mix_w2 + (size_t)r * D) : mix_b2;
                float4 f1 = *(const float4*)(src + i0);
                float4 f2 = *(const float4*)(src + i0 + 4);
                o[0]=f2b(f1.x); o[1]=f2b(f1.y); o[2]=f2b(f1.z); o[3]=f2b(f1.w);
                o[4]=f2b(f2.x); o[5]=f2b(f2.y); o[6]=f2b(f2.z); o[7]=f2b(f2.w);
            } else {
                o[0]=0;o[1]=0;o[2]=0;o[3]=0;o[4]=0;o[5]=0;o[6]=0;o[7]=0;
            }
            *(u16x8*)(dst + (size_t)r*D + i0) = o;
        }
    } else if (bid < 181) {
        int k0 = (bid - 165) * 128;
        float (*tile)[66] = (float(*)[66])sbuf;
        for (int i = t; i < 128*65; i += 256) {
            int r = i / 65;
            tile[r][i - 65*r] = clf_w[(size_t)k0*65 + i];
        }
        __syncthreads();
        unsigned short* cwt = (unsigned short*)(ws + OFF_CWT);
        for (int idx = t; idx < 80*16; idx += 256) {
            int c = idx >> 4, kq = idx & 15;
            u16x8 v;
            #pragma unroll
            for (int j = 0; j < 8; ++j)
                v[j] = (c < NC) ? f2b(tile[kq*8 + j][c]) : (unsigned short)0;
            *(u16x8*)(cwt + (size_t)c*D + k0 + kq*8) = v;
        }
    } else if (bid < 245) {
        int b = bid - 181;
        const float* src = all_f + (size_t)b * D;
        int i0 = t * 8;
        float4 f1 = *(const float4*)(src + i0);
        float4 f2 = *(const float4*)(src + i0 + 4);
        float s = f1.x*f1.x + f1.y*f1.y + f1.z*f1.z + f1.w*f1.w
                + f2.x*f2.x + f2.y*f2.y + f2.z*f2.z + f2.w*f2.w;
        s += __shfl_xor(s, 1);  s += __shfl_xor(s, 2);  s += __shfl_xor(s, 4);
        s += __shfl_xor(s, 8);  s += __shfl_xor(s, 16); s += __shfl_xor(s, 32);
        if ((t & 63) == 0) sbuf[t >> 6] = s;
        __syncthreads();
        float tot = sbuf[0] + sbuf[1] + sbuf[2] + sbuf[3];
        float rn = 1.f / fmaxf(sqrtf(tot), 1e-12f);
        unsigned short* fnb = (unsigned short*)(ws + OFF_FNB) + (size_t)b * D;
        unsigned short* afb = (unsigned short*)(ws + OFF_AFB) + (size_t)b * D;
        u16x8 on, oa;
        on[0]=f2b(f1.x*rn); on[1]=f2b(f1.y*rn); on[2]=f2b(f1.z*rn); on[3]=f2b(f1.w*rn);
        on[4]=f2b(f2.x*rn); on[5]=f2b(f2.y*rn); on[6]=f2b(f2.z*rn); on[7]=f2b(f2.w*rn);
        oa[0]=f2b(f1.x); oa[1]=f2b(f1.y); oa[2]=f2b(f1.z); oa[3]=f2b(f1.w);
        oa[4]=f2b(f2.x); oa[5]=f2b(f2.y); oa[6]=f2b(f2.z); oa[7]=f2b(f2.w);
        *(u16x8*)(fnb + i0) = on;
        *(u16x8*)(afb + i0) = oa;
    } else if (bid < 757) {
        int n0 = (bid - 245) * 2;
        unsigned short* dst = (unsigned short*)(ws + OFF_EMBB);
        int i0 = t * 8;
        for (int r = 0; r < 2; ++r) {
            const float* src = emb + (size_t)(n0 + r) * D;
            float4 f1 = *(const float4*)(src + i0);
            float4 f2 = *(const float4*)(src + i0 + 4);
            u16x8 o;
            o[0]=f2b(f1.x); o[1]=f2b(f1.y); o[2]=f2b(f1.z); o[3]=f2b(f1.w);
            o[4]=f2b(f2.x); o[5]=f2b(f2.y); o[6]=f2b(f2.z); o[7]=f2b(f2.w);
            *(u16x8*)(dst + (size_t)(n0 + r)*D + i0) = o;
        }
    } else {
        int rb = bid - 757;
        float (*tile)[33] = (float(*)[33])sbuf;
        int k0 = (rb >> 2) * 128, h0 = (rb & 3) * 32;
        int hh = t & 31, kk = t >> 5;
        for (int r = 0; r < 16; ++r)
            tile[kk + r*8][hh] = head_w1[(size_t)(k0 + kk + r*8)*HD + h0 + hh];
        __syncthreads();
        unsigned short* dst = (unsigned short*)(ws + OFF_W1T);
        int kcol = (t & 63) * 2, hrow = t >> 6;
        for (int r = 0; r < 8; ++r) {
            int h = hrow + r*4;
            u16x2 v;
            v[0] = f2b(tile[kcol][h]);
            v[1] = f2b(tile[kcol + 1][h]);
            *(u16x2*)(dst + (size_t)(h0 + h)*D + k0 + kcol) = v;
        }
    }
}

// ===================== K2: MFMA phase (512 thr, 243 blocks) =====================
// [0,128) attn ks=8 | [128,196) headzf K-split partials | [196,241) Wc | [241,243) px
__global__ void __launch_bounds__(512) k_main(const float* __restrict__ clf_b,
                                              float* __restrict__ ws) {
    __shared__ float part[2][32][128];
    __shared__ float wcp[8][16][16];
    int bid = blockIdx.x, t = threadIdx.x;
    int lane = t & 63, wv = t >> 6;
    int row16 = lane & 15, kgrp = lane >> 4;
    if (bid < 128) {
        const unsigned short* fnb  = (const unsigned short*)(ws + OFF_FNB);
        const unsigned short* embb = (const unsigned short*)(ws + OFF_EMBB);
        int nt = bid & 15, ks = bid >> 4;
        int b0 = (wv & 3) * 16;
        int n0 = nt*64 + (wv >> 2) * 32;
        const unsigned short* Ap = fnb  + (size_t)(b0 + row16)*D + ks*256 + kgrp*8;
        const unsigned short* B0 = embb + (size_t)(n0 + row16)*D + ks*256 + kgrp*8;
        const unsigned short* B1 = B0 + 16*D;
        f32x4 a0 = {0,0,0,0}, a1 = {0,0,0,0};
        #pragma unroll
        for (int s = 0; s < 8; ++s) {
            bf16x8 a = *(const bf16x8*)(Ap + s*32);
            a0 = __builtin_amdgcn_mfma_f32_16x16x32_bf16(a, *(const bf16x8*)(B0 + s*32), a0, 0, 0, 0);
            a1 = __builtin_amdgcn_mfma_f32_16x16x32_bf16(a, *(const bf16x8*)(B1 + s*32), a1, 0, 0, 0);
        }
        float* Sp = ws + OFF_SP + (size_t)ks * BSZ * NQ;
        #pragma unroll
        for (int r = 0; r < 4; ++r) {
            float* rowp = Sp + (size_t)(b0 + kgrp*4 + r)*NQ + n0;
            rowp[row16]      = a0[r];
            rowp[16 + row16] = a1[r];
        }
    } else if (bid < 196) {
        // ---- headzf K-split partials: role = (tile 0..33) x (kh 0..1) ----
        int role = bid - 128;
        int tile = role >> 1, kh = role & 1;
        bool isF = tile >= 32;
        const unsigned short* Arow = isF
            ? (const unsigned short*)(ws + OFF_AFB) + (size_t)(tile - 32) * 32 * D
            : (const unsigned short*)(ws + OFF_EMBB) + (size_t)tile * 32 * D;
        const unsigned short* w1t = (const unsigned short*)(ws + OFF_W1T);
        int hgrp = wv & 3, kq = wv >> 2;
        int koff = kh*1024 + kq*512;
        const unsigned short* Ap = Arow + (size_t)row16*D + koff + kgrp*8;
        const unsigned short* B0 = w1t + (size_t)(hgrp*32 + row16)*D + koff + kgrp*8;
        const unsigned short* B1 = B0 + 16*D;
        f32x4 h00 = {0,0,0,0}, h01 = {0,0,0,0}, h10 = {0,0,0,0}, h11 = {0,0,0,0};
        #pragma unroll 4
        for (int s = 0; s < 16; ++s) {
            bf16x8 a0 = *(const bf16x8*)(Ap + s*32);
            bf16x8 a1 = *(const bf16x8*)(Ap + 16*D + s*32);
            bf16x8 b0 = *(const bf16x8*)(B0 + s*32);
            bf16x8 b1 = *(const bf16x8*)(B1 + s*32);
            h00 = __builtin_amdgcn_mfma_f32_16x16x32_bf16(a0, b0, h00, 0, 0, 0);
            h01 = __builtin_amdgcn_mfma_f32_16x16x32_bf16(a0, b1, h01, 0, 0, 0);
            h10 = __builtin_amdgcn_mfma_f32_16x16x32_bf16(a1, b0, h10, 0, 0, 0);
            h11 = __builtin_amdgcn_mfma_f32_16x16x32_bf16(a1, b1, h11, 0, 0, 0);
        }
        int mb = kgrp*4, hc0 = hgrp*32 + row16, hc1 = hc0 + 16;
        #pragma unroll
        for (int r = 0; r < 4; ++r) {
            part[kq][mb + r][hc0]      = h00[r];
            part[kq][mb + r][hc1]      = h01[r];
            part[kq][16 + mb + r][hc0] = h10[r];
            part[kq][16 + mb + r][hc1] = h11[r];
        }
        __syncthreads();
        int row = t >> 4, c8 = (t & 15) * 8;
        float* dst = ws + OFF_H1P + (size_t)kh*1088*HD + (size_t)(tile*32 + row)*HD + c8;
        float4 o0, o1;
        o0.x = part[0][row][c8+0] + part[1][row][c8+0];
        o0.y = part[0][row][c8+1] + part[1][row][c8+1];
        o0.z = part[0][row][c8+2] + part[1][row][c8+2];
        o0.w = part[0][row][c8+3] + part[1][row][c8+3];
        o1.x = part[0][row][c8+4] + part[1][row][c8+4];
        o1.y = part[0][row][c8+5] + part[1][row][c8+5];
        o1.z = part[0][row][c8+6] + part[1][row][c8+6];
        o1.w = part[0][row][c8+7] + part[1][row][c8+7];
        *(float4*)dst = o0;
        *(float4*)(dst + 4) = o1;
    } else if (bid < 241) {
        // ---- Wc GEMM ----
        int w = bid - 196;
        int mt = w / 5, ntile = w % 5;
        const unsigned short* mw2b = (const unsigned short*)(ws + OFF_MW2B);
        const unsigned short* cwt  = (const unsigned short*)(ws + OFF_CWT);
        const unsigned short* Ap = mw2b + (size_t)(mt*16 + row16)*D + wv*256 + kgrp*8;
        const unsigned short* Bp = cwt  + (size_t)(ntile*16 + row16)*D + wv*256 + kgrp*8;
        f32x4 acc = {0,0,0,0};
        #pragma unroll
        for (int s = 0; s < 8; ++s)
            acc = __builtin_amdgcn_mfma_f32_16x16x32_bf16(
                *(const bf16x8*)(Ap + s*32), *(const bf16x8*)(Bp + s*32), acc, 0, 0, 0);
        #pragma unroll
        for (int r = 0; r < 4; ++r)
            wcp[wv][kgrp*4 + r][row16] = acc[r];
        __syncthreads();
        if (t < 256) {
            int j = t >> 4, c16 = t & 15;
            float s = 0.f;
            #pragma unroll
            for (int q = 0; q < 8; ++q) s += wcp[q][j][c16];
            int jj = mt*16 + j, c = ntile*16 + c16;
            unsigned short* wct = (unsigned short*)(ws + OFF_WC);
            if (jj < HD)       wct[(size_t)c*HD + jj] = f2b(s);
            else if (jj == HD) ws[OFF_BVEC + c] = (c < NC) ? s + clf_b[c] : -1e30f;
        }
    } else {
        // ---- px partials ----
        int pb = bid - 241;
        const unsigned short* fnb = (const unsigned short*)(ws + OFF_FNB);
        int bq = wv & 3, kq = (wv >> 2) + pb*2;
        int b0 = bq*16;
        const unsigned short* Ap = fnb + (size_t)(b0 + row16)*D + kq*512 + kgrp*8;
        const unsigned short* Bp = fnb + (size_t)row16*D + kq*512 + kgrp*8;
        f32x4 acc[4];
        #pragma unroll
        for (int nt = 0; nt < 4; ++nt) acc[nt] = (f32x4){0.f,0.f,0.f,0.f};
        #pragma unroll 2
        for (int s = 0; s < 16; ++s) {
            bf16x8 a = *(const bf16x8*)(Ap + s*32);
            #pragma unroll
            for (int nt = 0; nt < 4; ++nt)
                acc[nt] = __builtin_amdgcn_mfma_f32_16x16x32_bf16(
                    a, *(const bf16x8*)(Bp + (size_t)nt*16*D + s*32), acc[nt], 0, 0, 0);
        }
        #pragma unroll
        for (int r = 0; r < 4; ++r) {
            float v = acc[0][r] + acc[1][r] + acc[2][r] + acc[3][r];
            v += __shfl_xor(v, 1); v += __shfl_xor(v, 2);
            v += __shfl_xor(v, 4); v += __shfl_xor(v, 8);
            if (row16 == 0)
                ws[OFF_PXP + kq*64 + b0 + kgrp*4 + r] = v;
        }
    }
}

// ===================== K3: per-block headzf finish + mixer + SUMX ==================
// 512 blocks x 512 thr, 2 n each, 2 blocks/CU (LDS 76.5 KB). 3 barriers total:
// [stage WcT + build all 96 ush rows] sync [24 finish-MFMA tasks -> a2s/b2s bf16]
// sync [single-pass mixer] sync [SUMX store].
__global__ void __launch_bounds__(512, 4) k_mixfin(const float* __restrict__ ws,
                                                   float* __restrict__ wsw) {
    __shared__ unsigned short wcs[80][136];
    __shared__ unsigned short ushA[96][136];
    __shared__ unsigned short a2s[64][136];
    __shared__ unsigned short b2s[32][136];
    __shared__ float redp[8][80];
    int bid = blockIdx.x, t = threadIdx.x;
    int lane = t & 63, wv = t >> 6;
    int row16 = lane & 15, kgrp = lane >> 4;

    // stage WcT
    const unsigned short* wct = (const unsigned short*)(ws + OFF_WC);
    for (int i = t; i < 80*16; i += 512) {
        int r = i >> 4, cc = (i & 15) * 8;
        *(u16x8*)&wcs[r][cc] = *(const u16x8*)(wct + (size_t)r*HD + cc);
    }

    // build all ush rows: 0..31 = B2 tile (bid>>4), 32..95 = A2 tiles
    int tb = bid >> 4;
    int frow = t >> 4, fc8 = (t & 15) * 8;
    #pragma unroll
    for (int g = 0; g < 3; ++g) {
        int u = frow + g*32;
        int h1row = (u < 32) ? (tb*32 + u) : (1024 + (u - 32));
        const float* h0p = ws + OFF_H1P + (size_t)h1row*HD + fc8;
        const float* h1p = h0p + (size_t)1088*HD;
        #pragma unroll
        for (int j = 0; j < 8; ++j) {
            int col = fc8 + j;
            float v = h0p[j] + h1p[j];
            ushA[u][col] = f2b(fmaxf(fmaf(v, ws[OFF_SCALEH + col], ws[OFF_CH + col]), 0.f));
        }
    }

    // p_x from partials (shuffle-only, no LDS)
    const float invTS = 1.0f / (0.07f * 8.0f);
    float sv = (ws[OFF_PXP + lane] + ws[OFF_PXP + 64 + lane]
              + ws[OFF_PXP + 128 + lane] + ws[OFF_PXP + 192 + lane]) * invTS;
    float m2 = sv;
    m2 = fmaxf(m2, __shfl_xor(m2, 1));  m2 = fmaxf(m2, __shfl_xor(m2, 2));
    m2 = fmaxf(m2, __shfl_xor(m2, 4));  m2 = fmaxf(m2, __shfl_xor(m2, 8));
    m2 = fmaxf(m2, __shfl_xor(m2, 16)); m2 = fmaxf(m2, __shfl_xor(m2, 32));
    float e2 = __expf(sv - m2);
    float ssum = e2;
    ssum += __shfl_xor(ssum, 1);  ssum += __shfl_xor(ssum, 2);  ssum += __shfl_xor(ssum, 4);
    ssum += __shfl_xor(ssum, 8);  ssum += __shfl_xor(ssum, 16); ssum += __shfl_xor(ssum, 32);
    float px = e2 / ssum;
    float bvl[5];
    #pragma unroll
    for (int ct = 0; ct < 5; ++ct) bvl[ct] = ws[OFF_BVEC + ct*16 + row16];
    __syncthreads();   // ushA ready

    // finish MFMA: 24 tasks (6 row-tiles x 4 col-groups), 3 per wave
    #pragma unroll
    for (int i = 0; i < 3; ++i) {
        int task = wv + i*8;
        int rt6 = task >> 2, cg = task & 3;
        bool isF = rt6 >= 2;
        const unsigned short* wt = (const unsigned short*)(ws + (isF ? OFF_WAT : OFF_WZT));
        const unsigned short* W0 = wt + (size_t)(cg*32 + row16)*HD + kgrp*8;
        const unsigned short* W1b = W0 + 16*HD;
        f32x4 o0 = {0,0,0,0}, o1 = {0,0,0,0};
        #pragma unroll
        for (int s = 0; s < 4; ++s) {
            bf16x8 a = *(const bf16x8*)(&ushA[rt6*16 + row16][s*32 + kgrp*8]);
            o0 = __builtin_amdgcn_mfma_f32_16x16x32_bf16(a, *(const bf16x8*)(W0 + s*32), o0, 0, 0, 0);
            o1 = __builtin_amdgcn_mfma_f32_16x16x32_bf16(a, *(const bf16x8*)(W1b + s*32), o1, 0, 0, 0);
        }
        int hcA = cg*32 + row16, hcB = hcA + 16;
        int boff = isF ? OFF_BAC : OFF_BZC;
        float bz0 = ws[boff + hcA], bz1 = ws[boff + hcB];
        #pragma unroll
        for (int r = 0; r < 4; ++r) {
            int orow = rt6*16 + kgrp*4 + r;
            if (orow < 32) {
                b2s[orow][hcA] = f2b(o0[r] + bz0);
                b2s[orow][hcB] = f2b(o1[r] + bz1);
            } else {
                a2s[orow - 32][hcA] = f2b(o0[r] + bz0);
                a2s[orow - 32][hcB] = f2b(o1[r] + bz1);
            }
        }
    }
    __syncthreads();   // a2s/b2s ready

    // ---- mixer: single pass, n = bid*2 + ng ----
    int bt = wv & 3, ng = wv >> 2;
    u16x8 a2f[4];
    #pragma unroll
    for (int kt = 0; kt < 4; ++kt)
        a2f[kt] = *(const u16x8*)&a2s[bt*16 + row16][kt*32 + kgrp*8];
    int b2row = (bid & 15)*2 + ng;
    bf16x8 af[4];
    #pragma unroll
    for (int kt = 0; kt < 4; ++kt) {
        u16x8 bv = *(const u16x8*)&b2s[b2row][kt*32 + kgrp*8];
        bf16x8 v;
        #pragma unroll
        for (int j = 0; j < 8; ++j)
            v[j] = (short)f2b(fmaxf(bf2f(a2f[kt][j]) + bf2f(bv[j]), 0.f));
        af[kt] = v;
    }
    f32x4 acc[5];
    #pragma unroll
    for (int ct = 0; ct < 5; ++ct) acc[ct] = (f32x4){0.f,0.f,0.f,0.f};
    #pragma unroll
    for (int ct = 0; ct < 5; ++ct)
        #pragma unroll
        for (int kt = 0; kt < 4; ++kt)
            acc[ct] = __builtin_amdgcn_mfma_f32_16x16x32_bf16(
                af[kt], *(const bf16x8*)(&wcs[ct*16 + row16][kt*32 + kgrp*8]),
                acc[ct], 0, 0, 0);
    float outp[5] = {0.f, 0.f, 0.f, 0.f, 0.f};
    #pragma unroll
    for (int r = 0; r < 4; ++r) {
        float v0 = acc[0][r] + bvl[0];
        float v1 = acc[1][r] + bvl[1];
        float v2 = acc[2][r] + bvl[2];
        float v3 = acc[3][r] + bvl[3];
        float v4 = acc[4][r] + bvl[4];
        float m = fmaxf(fmaxf(fmaxf(v0, v1), fmaxf(v2, v3)), v4);
        m = fmaxf(m, __shfl_xor(m, 1)); m = fmaxf(m, __shfl_xor(m, 2));
        m = fmaxf(m, __shfl_xor(m, 4)); m = fmaxf(m, __shfl_xor(m, 8));
        float e0 = __expf(v0 - m), e1 = __expf(v1 - m), e2v = __expf(v2 - m);
        float e3 = __expf(v3 - m), e4 = __expf(v4 - m);
        float s = e0 + e1 + e2v + e3 + e4;
        s += __shfl_xor(s, 1); s += __shfl_xor(s, 2);
        s += __shfl_xor(s, 4); s += __shfl_xor(s, 8);
        float pxr = __shfl(px, bt*16 + kgrp*4 + r);
        float scale = pxr / s;
        outp[0] = fmaf(e0, scale, outp[0]);
        outp[1] = fmaf(e1, scale, outp[1]);
        outp[2] = fmaf(e2v, scale, outp[2]);
        outp[3] = fmaf(e3, scale, outp[3]);
        outp[4] = fmaf(e4, scale, outp[4]);
    }
    #pragma unroll
    for (int ct = 0; ct < 5; ++ct) {
        float v = outp[ct];
        v += __shfl_xor(v, 16); v += __shfl_xor(v, 32);
        outp[ct] = v;
    }
    if (kgrp == 0) {
        #pragma unroll
        for (int ct = 0; ct < 5; ++ct) redp[wv][ct*16 + row16] = outp[ct];
    }
    __syncthreads();
    if (t < 160) {
        int half = (t >= 80) ? 1 : 0;
        int c = t - 80*half;
        int nn = bid*2 + half;
        wsw[OFF_SUMX + (size_t)nn*80 + c] =
            redp[half*4 + 0][c] + redp[half*4 + 1][c]
          + redp[half*4 + 2][c] + redp[half*4 + 3][c];
    }
}

// ===================== K4: z_x softmax (no-max: |logit|<=0.45) + out matvec ========
// 256 blocks x 512 thr: block = (b, class-quarter). ~112 KB reads/block.
__global__ void __launch_bounds__(512) k_outz(const float* __restrict__ ws, float* __restrict__ out) {
    __shared__ float red8s[8];
    __shared__ float zrow[NQ];
    __shared__ float parts[8][20];
    int bid = blockIdx.x, t = threadIdx.x;
    int lane = t & 63, wvv = t >> 6;
    int b = bid >> 2, cq = bid & 3;
    const float invTS = 1.0f / (0.07f * 32.0f);
    const float* Sp = ws + OFF_SP + (size_t)b * NQ;
    float s0 = 0.f, s1 = 0.f;
    #pragma unroll
    for (int p = 0; p < 8; ++p) {
        s0 += Sp[(size_t)p*BSZ*NQ + t];
        s1 += Sp[(size_t)p*BSZ*NQ + 512 + t];
    }
    // logits are cosines * 1/(T*32) -> bounded by ~0.45; skip max subtraction
    float e0 = __expf(s0 * invTS), e1 = __expf(s1 * invTS);
    float ss = e0 + e1;
    ss += __shfl_xor(ss, 1);  ss += __shfl_xor(ss, 2);  ss += __shfl_xor(ss, 4);
    ss += __shfl_xor(ss, 8);  ss += __shfl_xor(ss, 16); ss += __shfl_xor(ss, 32);
    if (lane == 0) red8s[wvv] = ss;
    __syncthreads();
    float S = red8s[0] + red8s[1] + red8s[2] + red8s[3]
            + red8s[4] + red8s[5] + red8s[6] + red8s[7];
    float inv = 1.f / S;
    zrow[t]       = e0 * inv;
    zrow[512 + t] = e1 * inv;
    __syncthreads();
    const float* Sx = ws + OFF_SUMX;
    int nbase = wvv * 128;
    if (lane < 20) {
        int c = cq*20 + lane;
        float a0 = 0.f;
        #pragma unroll 8
        for (int k = 0; k < 128; ++k)
            a0 = fmaf(zrow[nbase + k], Sx[(size_t)(nbase + k)*80 + c], a0);
        parts[wvv][lane] = a0;
    }
    __syncthreads();
    if (t < 20) {
        int cg = cq*20 + t;
        if (cg < NC) {
            float s = 0.f;
            #pragma unroll
            for (int q = 0; q < 8; ++q) s += parts[q][t];
            out[b*NC + cg] = s;
        }
    }
}

extern "C" void kernel_launch(void* const* d_in, const int* in_sizes, int n_in,
                              void* d_out, int out_size, void* d_ws, size_t ws_size,
                              hipStream_t stream) {
    const float* all_f    = (const float*)d_in[0];
    const float* emb      = (const float*)d_in[1];
    const float* head_w1  = (const float*)d_in[3];
    const float* head_b1  = (const float*)d_in[4];
    const float* head_g   = (const float*)d_in[5];
    const float* head_beta= (const float*)d_in[6];
    const float* head_rm  = (const float*)d_in[7];
    const float* head_rv  = (const float*)d_in[8];
    const float* head_w2  = (const float*)d_in[9];
    const float* head_b2  = (const float*)d_in[10];
    const float* mix_w1   = (const float*)d_in[11];
    const float* mix_b1   = (const float*)d_in[12];
    const float* mix_g    = (const float*)d_in[13];
    const float* mix_beta = (const float*)d_in[14];
    const float* mix_rm   = (const float*)d_in[15];
    const float* mix_rv   = (const float*)d_in[16];
    const float* mix_w2   = (const float*)d_in[17];
    const float* mix_b2   = (const float*)d_in[18];
    const float* clf_w    = (const float*)d_in[19];
    const float* clf_b    = (const float*)d_in[20];
    float* ws  = (float*)d_ws;
    float* out = (float*)d_out;

    hipLaunchKernelGGL(k_prep, dim3(821), dim3(256), 0, stream,
                       all_f, emb, head_w1, head_b1, head_g, head_beta, head_rm, head_rv,
                       head_w2, head_b2, mix_w1, mix_b1, mix_g, mix_beta, mix_rm, mix_rv,
                       mix_w2, mix_b2, clf_w, ws);
    hipLaunchKernelGGL(k_main,   dim3(243), dim3(512), 0, stream, clf_b, ws);
    hipLaunchKernelGGL(k_mixfin, dim3(512), dim3(512), 0, stream, ws, ws);
    hipLaunchKernelGGL(k_outz,   dim3(256), dim3(512), 0, stream, ws, out);
}